// Round 1
// baseline (794.205 us; speedup 1.0000x reference)
//
#include <hip/hip_runtime.h>
#include <math.h>

// ---------------------------------------------------------------------------
// Problem shape (compile-time constants):
//   x: [6144] fp32; 6 layers 6144x6144 + ReLU; 1 layer 4096x6144 + Swish.
//   Outputs: [4M] pdist(x.reshape(2048,3)), [4M] pdist(y.reshape(2048,2)),
//            [4096] y.   The scalar "min" offset cancels in the pairwise
//            differences, so it is never computed.
// Bottleneck: streaming ~1007 MB of fp32 weights from HBM (GEMV chain).
// ---------------------------------------------------------------------------

#define K_DIM 6144   // input dim of every layer

// One 64-lane wave per output row. float4 loads: lane reads 16B, wave reads
// 1KB per iteration, 24 iterations covers the 24KB row. x is 24KB -> L1-hit.
template<bool RELU>
__global__ __launch_bounds__(256) void gemv_k6144(
    const float* __restrict__ W, const float* __restrict__ b,
    const float* __restrict__ x, float* __restrict__ out, int nRows)
{
    const int gwave = (blockIdx.x * 256 + threadIdx.x) >> 6;
    const int lane  = threadIdx.x & 63;
    if (gwave >= nRows) return;

    const float4* __restrict__ Wr = (const float4*)(W + (size_t)gwave * K_DIM);
    const float4* __restrict__ xv = (const float4*)x;

    float acc = 0.f;
#pragma unroll
    for (int i = 0; i < K_DIM / 256; ++i) {   // 24 iterations
        float4 w = Wr[i * 64 + lane];
        float4 v = xv[i * 64 + lane];
        acc = fmaf(w.x, v.x, acc);
        acc = fmaf(w.y, v.y, acc);
        acc = fmaf(w.z, v.z, acc);
        acc = fmaf(w.w, v.w, acc);
    }

    // 64-lane wave reduction
#pragma unroll
    for (int off = 32; off > 0; off >>= 1)
        acc += __shfl_down(acc, off, 64);

    if (lane == 0) {
        float z = acc + b[gwave];
        float r;
        if (RELU) {
            r = fmaxf(z, 0.f);
        } else {
            // Swish: z * sigmoid(z)
            r = z / (1.f + expf(-z));
        }
        out[gwave] = r;
    }
}

// Pairwise L2 distance, 3-dim points (input side). 2048x2048 outputs.
// x is 24KB -> fully cached; cost is the 16MB coalesced write.
__global__ __launch_bounds__(256) void pdist3_kernel(
    const float* __restrict__ x, float* __restrict__ out)
{
    const int idx = blockIdx.x * 256 + threadIdx.x;   // 0 .. 2048*2048-1
    const int n = idx >> 11;
    const int m = idx & 2047;
    float a0 = x[3 * n + 0], a1 = x[3 * n + 1], a2 = x[3 * n + 2];
    float c0 = x[3 * m + 0], c1 = x[3 * m + 1], c2 = x[3 * m + 2];
    float d0 = a0 - c0, d1 = a1 - c1, d2 = a2 - c2;
    float s = d0 * d0 + d1 * d1 + d2 * d2;
    out[idx] = (s > 0.f) ? sqrtf(s) : 0.f;
}

// Pairwise L2 distance, 2-dim points (latent side).
__global__ __launch_bounds__(256) void pdist2_kernel(
    const float* __restrict__ y, float* __restrict__ out)
{
    const int idx = blockIdx.x * 256 + threadIdx.x;
    const int n = idx >> 11;
    const int m = idx & 2047;
    float a0 = y[2 * n + 0], a1 = y[2 * n + 1];
    float c0 = y[2 * m + 0], c1 = y[2 * m + 1];
    float d0 = a0 - c0, d1 = a1 - c1;
    float s = d0 * d0 + d1 * d1;
    out[idx] = (s > 0.f) ? sqrtf(s) : 0.f;
}

extern "C" void kernel_launch(void* const* d_in, const int* in_sizes, int n_in,
                              void* d_out, int out_size, void* d_ws, size_t ws_size,
                              hipStream_t stream)
{
    const float* x  = (const float*)d_in[0];
    const float* W1 = (const float*)d_in[1];   const float* b1 = (const float*)d_in[2];
    const float* W2 = (const float*)d_in[3];   const float* b2 = (const float*)d_in[4];
    const float* W3 = (const float*)d_in[5];   const float* b3 = (const float*)d_in[6];
    const float* W4 = (const float*)d_in[7];   const float* b4 = (const float*)d_in[8];
    const float* W5 = (const float*)d_in[9];   const float* b5 = (const float*)d_in[10];
    const float* W6 = (const float*)d_in[11];  const float* b6 = (const float*)d_in[12];
    const float* W7 = (const float*)d_in[13];  const float* b7 = (const float*)d_in[14];

    float* out      = (float*)d_out;
    float* in_dist  = out;                       // 2048*2048
    float* lat_dist = out + 2048 * 2048;         // 2048*2048
    float* y        = out + 2 * 2048 * 2048;     // 4096 (lat_repr lives here)

    float* hA = (float*)d_ws;                    // 6144 floats
    float* hB = hA + K_DIM;                      // 6144 floats

    const int BS = 256;
    const int g6144 = 6144 / 4;   // 4 waves/block, one row per wave
    const int g4096 = 4096 / 4;
    const int gPD   = (2048 * 2048) / BS;

    // Input-side distances depend only on x — run first.
    pdist3_kernel<<<gPD, BS, 0, stream>>>(x, in_dist);

    // GEMV chain (sequential data dependence).
    gemv_k6144<true ><<<g6144, BS, 0, stream>>>(W1, b1, x,  hA, 6144);
    gemv_k6144<true ><<<g6144, BS, 0, stream>>>(W2, b2, hA, hB, 6144);
    gemv_k6144<true ><<<g6144, BS, 0, stream>>>(W3, b3, hB, hA, 6144);
    gemv_k6144<true ><<<g6144, BS, 0, stream>>>(W4, b4, hA, hB, 6144);
    gemv_k6144<true ><<<g6144, BS, 0, stream>>>(W5, b5, hB, hA, 6144);
    gemv_k6144<true ><<<g6144, BS, 0, stream>>>(W6, b6, hA, hB, 6144);
    gemv_k6144<false><<<g4096, BS, 0, stream>>>(W7, b7, hB, y,  4096);

    // Latent-side distances read y straight out of d_out.
    pdist2_kernel<<<gPD, BS, 0, stream>>>(y, lat_dist);
}